// Round 7
// baseline (858.641 us; speedup 1.0000x reference)
//
#include <hip/hip_runtime.h>

#define N_NODES  500000
#define HIDDEN   256
#define N_GRAPHS 8192

typedef float f32x4 __attribute__((ext_vector_type(4)));
typedef short s16x8 __attribute__((ext_vector_type(8)));

__device__ __forceinline__ unsigned short f2bf(float f) {
    unsigned int u = __float_as_uint(f);
    u += 0x7fffu + ((u >> 16) & 1u);   // RNE round to bf16
    return (unsigned short)(u >> 16);
}

// Pack W1 [K=256][N=256] fp32 into bf16 B-fragments, grouped per wave-slice.
// slot = (wave*8 + kt)*4 + ntp ; nt = wave*4 + ntp
// w1pack[(slot*64 + lane)*8 + j] = bf16( W1[kt*32 + (lane>>4)*8 + j][nt*16 + (lane&15)] )
__global__ void prep_w1_kernel(const float* __restrict__ W1,
                               unsigned short* __restrict__ w1pack) {
    int tid  = blockIdx.x * 256 + threadIdx.x;   // 0..8191
    int lane = tid & 63;
    int slot = tid >> 6;                         // 0..127
    int wv   = slot >> 5;
    int kt   = (slot >> 2) & 7;
    int ntp  = slot & 3;
    int nt   = wv * 4 + ntp;
    int krow = kt * 32 + ((lane >> 4) & 3) * 8;
    int col  = nt * 16 + (lane & 15);
    unsigned short tmp[8];
#pragma unroll
    for (int j = 0; j < 8; ++j)
        tmp[j] = f2bf(W1[(size_t)(krow + j) * 256 + col]);
    *(uint4*)(w1pack + (size_t)tid * 8) = *(const uint4*)tmp;
}

// offsEnd[g] = lower_bound(batch, g+1)  (end of graph g's sorted range)
__global__ void offsets_kernel(const int* __restrict__ batch,
                               int* __restrict__ offsEnd) {
    int g = blockIdx.x * 256 + threadIdx.x;      // 0..8191
    if (g >= N_GRAPHS) return;
    int lo = 0, hi = N_NODES;
    while (lo < hi) {
        int mid = (lo + hi) >> 1;
        if (batch[mid] < g + 1) lo = mid + 1; else hi = mid;
    }
    offsEnd[g] = lo;
}

// One block per GRAPH. 256 threads = 4 waves; wave w owns output cols [64w,64w+64)
// for the GEMM (N-split) and rows [16w,16w+16) of each chunk for the weighted sum.
// LDS: bf16 x chunk [64][32 units], XOR-swizzled (32 KiB) + partials. 4 blocks/CU.
__launch_bounds__(256, 4)
__global__ void attn_pool_graph(const float* __restrict__ x,
                                const float* __restrict__ b1,
                                const float* __restrict__ W2,
                                const float* __restrict__ b2,
                                const unsigned short* __restrict__ w1pack,
                                const int* __restrict__ offsEnd,
                                float* __restrict__ out) {
    __shared__ unsigned short xbf[64 * 256];   // 32 KiB
    __shared__ float plds[256];                // logit partials [wave][row]
    __shared__ float accs[4 * 256];            // final cross-wave numerator
    __shared__ float dsum[4];                  // final cross-wave denominator

    const int tid  = threadIdx.x;
    const int wave = tid >> 6;
    const int lane = tid & 63;
    const int cl   = lane & 15;
    const int kgrp = lane >> 4;
    const int g    = blockIdx.x;

    const int nend   = offsEnd[g];
    const int nstart = (g == 0) ? 0 : offsEnd[g - 1];
    const int count  = nend - nstart;
    const int nchunks = (count + 63) >> 6;

    float b1c[4], w2c[4];
#pragma unroll
    for (int ntp = 0; ntp < 4; ++ntp) {
        int nt = wave * 4 + ntp;
        b1c[ntp] = b1[nt * 16 + cl];
        w2c[ntp] = W2[nt * 16 + cl];
    }
    const float b2v = b2[0];

    f32x4 accv = {0.f, 0.f, 0.f, 0.f};
    float accden = 0.f;

    for (int c = 0; c < nchunks; ++c) {
        const int cbase = nstart + c * 64;

        // ---- stage chunk -> bf16 LDS; 16B-unit index ^= (row&7) ----
#pragma unroll
        for (int i = 0; i < 8; ++i) {
            int v   = tid + i * 256;      // 0..2047
            int row = v >> 5;
            int cu  = v & 31;
            f32x4 a = {0.f, 0.f, 0.f, 0.f}, cc = {0.f, 0.f, 0.f, 0.f};
            int node = cbase + row;
            if (node < nend) {
                const float* p = x + (size_t)node * HIDDEN + cu * 8;
                a  = *(const f32x4*)p;
                cc = *(const f32x4*)(p + 4);
            }
            s16x8 w;
            w[0] = (short)f2bf(a[0]);  w[1] = (short)f2bf(a[1]);
            w[2] = (short)f2bf(a[2]);  w[3] = (short)f2bf(a[3]);
            w[4] = (short)f2bf(cc[0]); w[5] = (short)f2bf(cc[1]);
            w[6] = (short)f2bf(cc[2]); w[7] = (short)f2bf(cc[3]);
            *(s16x8*)(xbf + (size_t)(row * 32 + (cu ^ (row & 7))) * 8) = w;
        }
        __syncthreads();

        // ---- GEMM: A from bf16 LDS, B from L2-hot w1pack ----
        f32x4 acc[4][4];
#pragma unroll
        for (int rt = 0; rt < 4; ++rt)
#pragma unroll
            for (int ntp = 0; ntp < 4; ++ntp)
                acc[rt][ntp] = (f32x4){0.f, 0.f, 0.f, 0.f};

#pragma unroll
        for (int kt = 0; kt < 8; ++kt) {
            s16x8 bf[4];
#pragma unroll
            for (int ntp = 0; ntp < 4; ++ntp)
                bf[ntp] = *(const s16x8*)(w1pack +
                    ((size_t)(((wave * 8 + kt) * 4 + ntp) * 64 + lane) << 3));
#pragma unroll
            for (int rt = 0; rt < 4; ++rt) {
                int row = rt * 16 + cl;
                int cu  = kt * 4 + kgrp;
                s16x8 af = *(const s16x8*)(xbf +
                    (size_t)(row * 32 + (cu ^ (row & 7))) * 8);
#pragma unroll
                for (int ntp = 0; ntp < 4; ++ntp)
                    acc[rt][ntp] = __builtin_amdgcn_mfma_f32_16x16x32_bf16(
                        af, bf[ntp], acc[rt][ntp], 0, 0, 0);
            }
        }

        // ---- tanh + partial logit over this wave's 64 cols ----
        float sj[4][4];
#pragma unroll
        for (int rt = 0; rt < 4; ++rt)
#pragma unroll
            for (int j = 0; j < 4; ++j) sj[rt][j] = 0.f;
#pragma unroll
        for (int rt = 0; rt < 4; ++rt)
#pragma unroll
            for (int ntp = 0; ntp < 4; ++ntp)
#pragma unroll
                for (int j = 0; j < 4; ++j) {
                    float h = acc[rt][ntp][j] + b1c[ntp];
                    h = fminf(fmaxf(h, -15.f), 15.f);
                    float e2 = __expf(2.f * h);
                    float th = (e2 - 1.f) * __builtin_amdgcn_rcpf(e2 + 1.f);
                    sj[rt][j] += th * w2c[ntp];
                }
#pragma unroll
        for (int m = 1; m < 16; m <<= 1)
#pragma unroll
            for (int rt = 0; rt < 4; ++rt)
#pragma unroll
                for (int j = 0; j < 4; ++j)
                    sj[rt][j] += __shfl_xor(sj[rt][j], m, 64);
        if (cl == 0) {
#pragma unroll
            for (int rt = 0; rt < 4; ++rt)
#pragma unroll
                for (int j = 0; j < 4; ++j)
                    plds[wave * 64 + rt * 16 + kgrp * 4 + j] = sj[rt][j];
        }
        __syncthreads();

        // ---- combine partials -> e per row (rows >= count masked to 0) ----
        int rr = wave * 16 + cl;
        float logit = plds[rr] + plds[64 + rr] + plds[128 + rr] + plds[192 + rr] + b2v;
        float el = (cbase + rr < nend) ? __expf(logit) : 0.f;

        // ---- weighted accumulation; x re-read fp32 (L2-hot, just staged) ----
#pragma unroll
        for (int r = 0; r < 16; ++r) {
            int node = cbase + wave * 16 + r;
            if (node < nend) {         // wave-uniform branch
                float er = __shfl(el, r, 64);
                f32x4 xv = *(const f32x4*)(x + (size_t)node * HIDDEN + lane * 4);
                accv += er * xv;
                accden += er;
            }
        }
        // next stage's xbf write is ordered by its own __syncthreads();
        // plds next written only after that barrier -> safe with 2 barriers/chunk
    }

    // ---- cross-wave reduction + single output write ----
    *(f32x4*)(accs + wave * 256 + lane * 4) = accv;
    if (lane == 0) dsum[wave] = accden;
    __syncthreads();
    if (wave == 0) {
        f32x4 t0 = *(const f32x4*)(accs + lane * 4);
        f32x4 t1 = *(const f32x4*)(accs + 256 + lane * 4);
        f32x4 t2 = *(const f32x4*)(accs + 512 + lane * 4);
        f32x4 t3 = *(const f32x4*)(accs + 768 + lane * 4);
        float d = dsum[0] + dsum[1] + dsum[2] + dsum[3] + 1e-8f;
        f32x4 tot = t0 + t1 + t2 + t3;
        f32x4 res;
        res[0] = tot[0] / d; res[1] = tot[1] / d;
        res[2] = tot[2] / d; res[3] = tot[3] / d;
        *(f32x4*)(out + (size_t)g * HIDDEN + lane * 4) = res;
    }
}

extern "C" void kernel_launch(void* const* d_in, const int* in_sizes, int n_in,
                              void* d_out, int out_size, void* d_ws, size_t ws_size,
                              hipStream_t stream) {
    const float* x     = (const float*)d_in[0];
    const int*   batch = (const int*)d_in[1];
    const float* W1    = (const float*)d_in[2];
    const float* b1    = (const float*)d_in[3];
    const float* W2    = (const float*)d_in[4];
    const float* b2    = (const float*)d_in[5];
    float* out = (float*)d_out;

    unsigned short* w1pack = (unsigned short*)d_ws;          // 128 KiB
    int* offsEnd = (int*)((char*)d_ws + 131072);             // 32 KiB (8192 ints)

    prep_w1_kernel<<<32, 256, 0, stream>>>(W1, w1pack);
    offsets_kernel<<<32, 256, 0, stream>>>(batch, offsEnd);

    attn_pool_graph<<<N_GRAPHS, 256, 0, stream>>>(x, b1, W2, b2, w1pack, offsEnd, out);
}

// Round 9
// 788.608 us; speedup vs baseline: 1.0888x; 1.0888x over previous
//
#include <hip/hip_runtime.h>

#define N_NODES  500000
#define HIDDEN   256
#define N_GRAPHS 8192

typedef float f32x4 __attribute__((ext_vector_type(4)));
typedef short s16x8 __attribute__((ext_vector_type(8)));

__device__ __forceinline__ unsigned short f2bf(float f) {
    unsigned int u = __float_as_uint(f);
    u += 0x7fffu + ((u >> 16) & 1u);   // RNE round to bf16
    return (unsigned short)(u >> 16);
}

// Pack W1 [K=256][N=256] fp32 into bf16 B-fragments, grouped per wave-slice.
// slot = (wave*8 + kt)*4 + ntp ; nt = wave*4 + ntp
// w1pack[(slot*64 + lane)*8 + j] = bf16( W1[kt*32 + (lane>>4)*8 + j][nt*16 + (lane&15)] )
__global__ void prep_w1_kernel(const float* __restrict__ W1,
                               unsigned short* __restrict__ w1pack) {
    int tid  = blockIdx.x * 256 + threadIdx.x;   // 0..8191
    int lane = tid & 63;
    int slot = tid >> 6;                         // 0..127
    int wv   = slot >> 5;
    int kt   = (slot >> 2) & 7;
    int ntp  = slot & 3;
    int nt   = wv * 4 + ntp;
    int krow = kt * 32 + ((lane >> 4) & 3) * 8;
    int col  = nt * 16 + (lane & 15);
    unsigned short tmp[8];
#pragma unroll
    for (int j = 0; j < 8; ++j)
        tmp[j] = f2bf(W1[(size_t)(krow + j) * 256 + col]);
    *(uint4*)(w1pack + (size_t)tid * 8) = *(const uint4*)tmp;
}

// offsEnd[g] = lower_bound(batch, g+1)  (end of graph g's sorted range)
__global__ void offsets_kernel(const int* __restrict__ batch,
                               int* __restrict__ offsEnd) {
    int g = blockIdx.x * 256 + threadIdx.x;      // 0..8191
    if (g >= N_GRAPHS) return;
    int lo = 0, hi = N_NODES;
    while (lo < hi) {
        int mid = (lo + hi) >> 1;
        if (batch[mid] < g + 1) lo = mid + 1; else hi = mid;
    }
    offsEnd[g] = lo;
}

// One block per GRAPH, 256 threads = 4 waves. No atomics: block owns its output row.
// GEMM is column-split into two passes of 32 cols/wave -> acc is 32 regs (no spill
// at the __launch_bounds__(256,4) 128-reg cap; round-7's 64-reg acc spilled ~1.4GB).
__launch_bounds__(256, 4)
__global__ void attn_pool_graph(const float* __restrict__ x,
                                const float* __restrict__ b1,
                                const float* __restrict__ W2,
                                const float* __restrict__ b2,
                                const unsigned short* __restrict__ w1pack,
                                const int* __restrict__ offsEnd,
                                float* __restrict__ out) {
    __shared__ unsigned short xbf[64 * 256];   // 32 KiB bf16 chunk, unit-swizzled
    __shared__ float plds[256];                // logit partials [wave][row]
    __shared__ float accs[4 * 256];            // final cross-wave numerator
    __shared__ float dsum[4];                  // final cross-wave denominator

    const int tid  = threadIdx.x;
    const int wave = tid >> 6;
    const int lane = tid & 63;
    const int cl   = lane & 15;
    const int kgrp = lane >> 4;
    const int g    = blockIdx.x;

    const int nend    = offsEnd[g];
    const int nstart  = (g == 0) ? 0 : offsEnd[g - 1];
    const int nchunks = (nend - nstart + 63) >> 6;

    float b1c[4], w2c[4];
#pragma unroll
    for (int ntp = 0; ntp < 4; ++ntp) {
        int nt = wave * 4 + ntp;
        b1c[ntp] = b1[nt * 16 + cl];
        w2c[ntp] = W2[nt * 16 + cl];
    }
    const float b2v = b2[0];

    f32x4 accv = {0.f, 0.f, 0.f, 0.f};
    float accden = 0.f;

    for (int c = 0; c < nchunks; ++c) {
        const int cbase = nstart + c * 64;

        // ---- stage chunk -> bf16 LDS; 16B-unit index ^= (row&7) ----
#pragma unroll
        for (int i = 0; i < 8; ++i) {
            int v   = tid + i * 256;      // 0..2047
            int row = v >> 5;
            int cu  = v & 31;
            f32x4 a = {0.f, 0.f, 0.f, 0.f}, cc = {0.f, 0.f, 0.f, 0.f};
            int node = cbase + row;
            if (node < nend) {
                const float* p = x + (size_t)node * HIDDEN + cu * 8;
                a  = *(const f32x4*)p;
                cc = *(const f32x4*)(p + 4);
            }
            s16x8 w;
            w[0] = (short)f2bf(a[0]);  w[1] = (short)f2bf(a[1]);
            w[2] = (short)f2bf(a[2]);  w[3] = (short)f2bf(a[3]);
            w[4] = (short)f2bf(cc[0]); w[5] = (short)f2bf(cc[1]);
            w[6] = (short)f2bf(cc[2]); w[7] = (short)f2bf(cc[3]);
            *(s16x8*)(xbf + (size_t)(row * 32 + (cu ^ (row & 7))) * 8) = w;
        }
        __syncthreads();

        // ---- GEMM + tanh, two column-halves (acc = 32 regs each pass) ----
        float sj[4][4];
#pragma unroll
        for (int rt = 0; rt < 4; ++rt)
#pragma unroll
            for (int j = 0; j < 4; ++j) sj[rt][j] = 0.f;

#pragma unroll
        for (int half = 0; half < 2; ++half) {
            f32x4 acc2[4][2];
#pragma unroll
            for (int rt = 0; rt < 4; ++rt)
#pragma unroll
                for (int p = 0; p < 2; ++p)
                    acc2[rt][p] = (f32x4){0.f, 0.f, 0.f, 0.f};

#pragma unroll
            for (int kt = 0; kt < 8; ++kt) {
                s16x8 bf[2];
#pragma unroll
                for (int p = 0; p < 2; ++p)
                    bf[p] = *(const s16x8*)(w1pack +
                        ((size_t)(((wave * 8 + kt) * 4 + half * 2 + p) * 64 + lane) << 3));
#pragma unroll
                for (int rt = 0; rt < 4; ++rt) {
                    int row = rt * 16 + cl;
                    int cu  = kt * 4 + kgrp;
                    s16x8 af = *(const s16x8*)(xbf +
                        (size_t)(row * 32 + (cu ^ (row & 7))) * 8);
#pragma unroll
                    for (int p = 0; p < 2; ++p)
                        acc2[rt][p] = __builtin_amdgcn_mfma_f32_16x16x32_bf16(
                            af, bf[p], acc2[rt][p], 0, 0, 0);
                }
            }

            // tanh + partial logit for these 32 cols
#pragma unroll
            for (int rt = 0; rt < 4; ++rt)
#pragma unroll
                for (int p = 0; p < 2; ++p) {
                    float bb = b1c[half * 2 + p];
                    float ww = w2c[half * 2 + p];
#pragma unroll
                    for (int j = 0; j < 4; ++j) {
                        float h = acc2[rt][p][j] + bb;
                        h = fminf(fmaxf(h, -15.f), 15.f);
                        float e2 = __expf(2.f * h);
                        float th = (e2 - 1.f) * __builtin_amdgcn_rcpf(e2 + 1.f);
                        sj[rt][j] += th * ww;
                    }
                }
        }

        // reduce across 16 lanes of each kgrp group
#pragma unroll
        for (int m = 1; m < 16; m <<= 1)
#pragma unroll
            for (int rt = 0; rt < 4; ++rt)
#pragma unroll
                for (int j = 0; j < 4; ++j)
                    sj[rt][j] += __shfl_xor(sj[rt][j], m, 64);
        if (cl == 0) {
#pragma unroll
            for (int rt = 0; rt < 4; ++rt)
#pragma unroll
                for (int j = 0; j < 4; ++j)
                    plds[wave * 64 + rt * 16 + kgrp * 4 + j] = sj[rt][j];
        }
        __syncthreads();

        // ---- combine partials -> e per row (masked past nend) ----
        int rr = wave * 16 + cl;
        float logit = plds[rr] + plds[64 + rr] + plds[128 + rr] + plds[192 + rr] + b2v;
        float el = (cbase + rr < nend) ? __expf(logit) : 0.f;

        // ---- weighted accumulation; x re-read fp32 (L2-hot, just staged) ----
#pragma unroll
        for (int r = 0; r < 16; ++r) {
            int node = cbase + wave * 16 + r;
            if (node < nend) {         // wave-uniform branch
                float er = __shfl(el, r, 64);
                f32x4 xv = *(const f32x4*)(x + (size_t)node * HIDDEN + lane * 4);
                accv += er * xv;
                accden += er;
            }
        }
        // 2 barriers/chunk: xbf reads all precede the plds barrier; next-chunk
        // xbf writes follow it; plds(c+1) writes are fenced by barrier B1(c+1).
    }

    // ---- cross-wave reduction + single output write ----
    *(f32x4*)(accs + wave * 256 + lane * 4) = accv;
    if (lane == 0) dsum[wave] = accden;
    __syncthreads();
    if (wave == 0) {
        f32x4 t0 = *(const f32x4*)(accs + lane * 4);
        f32x4 t1 = *(const f32x4*)(accs + 256 + lane * 4);
        f32x4 t2 = *(const f32x4*)(accs + 512 + lane * 4);
        f32x4 t3 = *(const f32x4*)(accs + 768 + lane * 4);
        float d = dsum[0] + dsum[1] + dsum[2] + dsum[3] + 1e-8f;
        f32x4 tot = t0 + t1 + t2 + t3;
        f32x4 res;
        res[0] = tot[0] / d; res[1] = tot[1] / d;
        res[2] = tot[2] / d; res[3] = tot[3] / d;
        *(f32x4*)(out + (size_t)g * HIDDEN + lane * 4) = res;
    }
}

extern "C" void kernel_launch(void* const* d_in, const int* in_sizes, int n_in,
                              void* d_out, int out_size, void* d_ws, size_t ws_size,
                              hipStream_t stream) {
    const float* x     = (const float*)d_in[0];
    const int*   batch = (const int*)d_in[1];
    const float* W1    = (const float*)d_in[2];
    const float* b1    = (const float*)d_in[3];
    const float* W2    = (const float*)d_in[4];
    const float* b2    = (const float*)d_in[5];
    float* out = (float*)d_out;

    unsigned short* w1pack = (unsigned short*)d_ws;          // 128 KiB
    int* offsEnd = (int*)((char*)d_ws + 131072);             // 32 KiB (8192 ints)

    prep_w1_kernel<<<32, 256, 0, stream>>>(W1, w1pack);
    offsets_kernel<<<32, 256, 0, stream>>>(batch, offsEnd);

    attn_pool_graph<<<N_GRAPHS, 256, 0, stream>>>(x, b1, W2, b2, w1pack, offsEnd, out);
}